// Round 16
// baseline (657.809 us; speedup 1.0000x reference)
//
#include <hip/hip_runtime.h>
#include <hip/hip_bf16.h>

// SDE Euler-Maruyama: x_{k+1} = x_k + dt*(x_k @ A^T) + (sigma*sqrt(dt))*dW_k
// out[0] = x0, out[k+1] = x_{k+1}, out shape [1001, 1024, 256].
//
// R11 440 / R12 408 / R14 424 / R15 419 (4-step fusion plateau, 1 blk/CU).
// R16: ANTI-PHASE 2 BLOCKS/CU. 512 blocks x 256 thr (4 waves), 2 paths per
// block. Tile = 8 real rows {x,nu0,nu1,nu2} x 2 paths (R = 4p + j); A-rows
// 8-15 duplicate 0-7 (replica trick) -> frag reads/CU unchanged. C/D group
// 0/1 = path 0/1 prefix terms (update role, fvec4 I/O on 4 adjacent cols);
// groups 2/3 (replica C/D, unused acc) take the nu-row staging role.
// 2x MFMA/CU (1240 cyc) fits under the ~3200-cyc HBM budget; independent
// per-block barriers let block A's MFMA cover block B's chain/barrier time.
// Numerics identical to R12: y_k = y_{k-1} + p_k + nu_{k-1},
// p_k = t0+..+t_{k-1}, t = (dt*A)*{x,nu...}; O(M^2) dropped (~1e-4).

typedef __attribute__((ext_vector_type(2))) float fvec2;
typedef __attribute__((ext_vector_type(4))) float fvec4;
typedef __attribute__((ext_vector_type(4))) unsigned short usvec4;
typedef __attribute__((ext_vector_type(8))) short svec8;
typedef __attribute__((ext_vector_type(4))) float f32x4;

constexpr int D = 256;
constexpr int BATCH = 1024;
constexpr int BD = BATCH * D;
constexpr int NSTEPS = 1000;
constexpr float DT = 0.001f;
constexpr float SQRT_DT = 0.03162277660168379f;  // sqrt(0.001)

__device__ __forceinline__ unsigned short f2bf(float f) {
  unsigned int u = __float_as_uint(f);
  u += 0x7FFFu + ((u >> 16) & 1u);
  return (unsigned short)(u >> 16);
}

// LDS-only barrier: no vmcnt drain (global loads/stores stay in flight).
__device__ __forceinline__ void lds_barrier() {
  __builtin_amdgcn_sched_barrier(0);
  asm volatile("s_waitcnt lgkmcnt(0)" ::: "memory");
  __builtin_amdgcn_s_barrier();
  __builtin_amdgcn_sched_barrier(0);
}

// xb u16 index for (row R, col c): XOR bits 4-6 -> frag-read bank spread is
// <=2-way; 4-u16 (b64) and 8-u16 (b128) runs stay contiguous (XOR bits >=4,
// run starts 4-/8-aligned).
#define XIDX(R, c) (((R) << 8) + ((c) ^ (((R)&3) << 5) ^ (((R)&4) << 2)))

__global__ __launch_bounds__(256, 2)
void sde_em_kernel(const float* __restrict__ x0, const float* __restrict__ Amat,
                   const float* __restrict__ sigma, const float* __restrict__ dW,
                   float* __restrict__ out) {
  // 8 rows (R = 4*path + j) x 256 cols bf16, double-buffered (8 KB)
  __shared__ __align__(16) unsigned short xb[2][8 * 256];

  const int t = threadIdx.x;
  const int w = t >> 6;          // wave 0..3: owns cols w*64 .. w*64+63
  const int l = t & 63;
  const int l16 = l & 15;
  const int q = l >> 4;          // lane group 0..3
  const int rr = l16 & 7;        // A-frag row (tile rows 8-15 duplicate 0-7)
  const int path = q & 1;        // group 0/2 -> path 0, 1/3 -> path 1
  const bool upd = (q < 2);      // groups 0/1 update; 2/3 stage nu rows

  // ---- one-time: B = DT*A^T fragments; chain tt -> out col c0 + tt ----
  svec8 bfr[4][8];
#pragma unroll
  for (int tt = 0; tt < 4; ++tt) {
#pragma unroll
    for (int kt = 0; kt < 8; ++kt) {
      const float* src =
          Amat + (size_t)((w << 6) + (l16 << 2) + tt) * D + (kt << 5) + (q << 3);
      fvec4 a0 = *(const fvec4*)(src);
      fvec4 a1 = *(const fvec4*)(src + 4);
      svec8 b;
      b[0] = (short)f2bf(DT * a0[0]); b[1] = (short)f2bf(DT * a0[1]);
      b[2] = (short)f2bf(DT * a0[2]); b[3] = (short)f2bf(DT * a0[3]);
      b[4] = (short)f2bf(DT * a1[0]); b[5] = (short)f2bf(DT * a1[1]);
      b[6] = (short)f2bf(DT * a1[2]); b[7] = (short)f2bf(DT * a1[3]);
      bfr[tt][kt] = b;
    }
  }

  // ---- per-lane role state ----
  const int c0 = (w << 6) + (l16 << 2);   // 4 adjacent cols
  const size_t go = (size_t)((blockIdx.x << 1) + path) * D + c0;
  const int xrow = path << 2;             // tile row of x for this path
  fvec4 sg = *(const fvec4*)(sigma + c0);
  sg *= SQRT_DT;

  fvec4 xs = (fvec4){0.f, 0.f, 0.f, 0.f};
  fvec4 dv[4];                            // upd: dW[n..n+3]
  fvec4 nus[3];                           // stager: dW[n+4..n+6]

  if (upd) {
    xs = *(const fvec4*)(x0 + go);
#pragma unroll
    for (int j = 0; j < 4; ++j)
      dv[j] = __builtin_nontemporal_load((const fvec4*)(dW + (size_t)j * BD + go));
    *(usvec4*)&xb[0][XIDX(xrow, c0)] =
        (usvec4){f2bf(xs[0]), f2bf(xs[1]), f2bf(xs[2]), f2bf(xs[3])};
  } else {
#pragma unroll
    for (int j = 0; j < 3; ++j) {
      fvec4 v = __builtin_nontemporal_load((const fvec4*)(dW + (size_t)j * BD + go));
      *(usvec4*)&xb[0][XIDX(xrow + 1 + j, c0)] =
          (usvec4){f2bf(sg[0] * v[0]), f2bf(sg[1] * v[1]),
                   f2bf(sg[2] * v[2]), f2bf(sg[3] * v[3])};
      nus[j] = __builtin_nontemporal_load(
          (const fvec4*)(dW + (size_t)(4 + j) * BD + go));
    }
  }

  // out[0] = x0 (block slice = 2 paths x 256 dims, fvec2/thread, coalesced)
  {
    const size_t g2 = (size_t)(blockIdx.x << 1) * D + (t << 1);
    fvec2 v = *(const fvec2*)(x0 + g2);
    __builtin_nontemporal_store(v, (fvec2*)(out + g2));
  }

  __syncthreads();

  for (int it = 0; it < NSTEPS / 4; ++it) {
    const int n = it << 2;
    const int rb = it & 1, wb = rb ^ 1;

    // prefetch (consumed next iter; full iter of latency cover)
    fvec4 pf[4];
    if (upd) {
#pragma unroll
      for (int j = 0; j < 4; ++j) {
        int i_ = n + 4 + j;
        i_ = (i_ < NSTEPS) ? i_ : (NSTEPS - 1);
        pf[j] = __builtin_nontemporal_load(
            (const fvec4*)(dW + (size_t)i_ * BD + go));
      }
    } else {
#pragma unroll
      for (int j = 0; j < 3; ++j) {
        int i_ = n + 8 + j;
        i_ = (i_ < NSTEPS) ? i_ : (NSTEPS - 1);
        pf[j] = __builtin_nontemporal_load(
            (const fvec4*)(dW + (size_t)i_ * BD + go));
      }
      // stage nu rows for next tile (steps n+4..n+6); wb was read last iter,
      // its reads completed at the last barrier -> safe to overwrite now
#pragma unroll
      for (int j = 0; j < 3; ++j)
        *(usvec4*)&xb[wb][XIDX(xrow + 1 + j, c0)] =
            (usvec4){f2bf(sg[0] * nus[j][0]), f2bf(sg[1] * nus[j][1]),
                     f2bf(sg[2] * nus[j][2]), f2bf(sg[3] * nus[j][3])};
    }

    // MFMA: 4 chains (adjacent out cols), 8 kt
    f32x4 acc[4];
    acc[0] = (f32x4){0.f, 0.f, 0.f, 0.f};
    acc[1] = (f32x4){0.f, 0.f, 0.f, 0.f};
    acc[2] = (f32x4){0.f, 0.f, 0.f, 0.f};
    acc[3] = (f32x4){0.f, 0.f, 0.f, 0.f};
#pragma unroll
    for (int kt = 0; kt < 8; ++kt) {
      svec8 a = *(const svec8*)&xb[rb][(rr << 8) +
          ((((kt << 5) + (q << 3)) ^ ((rr & 3) << 5)) ^ ((rr & 4) << 2))];
#pragma unroll
      for (int tt = 0; tt < 4; ++tt)
        acc[tt] = __builtin_amdgcn_mfma_f32_16x16x32_bf16(a, bfr[tt][kt],
                                                          acc[tt], 0, 0, 0);
    }

    if (upd) {
      // group q's regs ARE path q's prefix terms t0..t3 (col = c0 + tt)
      fvec4 p1, p2, p3, p4;
#pragma unroll
      for (int tt = 0; tt < 4; ++tt) {
        p1[tt] = acc[tt][0];
        p2[tt] = p1[tt] + acc[tt][1];
        p3[tt] = p2[tt] + acc[tt][2];
        p4[tt] = p3[tt] + acc[tt][3];
      }
      float* ob = out + (size_t)(n + 1) * BD + go;
#pragma unroll
      for (int tt = 0; tt < 4; ++tt)
        xs[tt] = __builtin_fmaf(sg[tt], dv[0][tt], xs[tt]) + p1[tt];
      __builtin_nontemporal_store(xs, (fvec4*)ob);
#pragma unroll
      for (int tt = 0; tt < 4; ++tt)
        xs[tt] = __builtin_fmaf(sg[tt], dv[1][tt], xs[tt]) + p2[tt];
      __builtin_nontemporal_store(xs, (fvec4*)(ob + BD));
#pragma unroll
      for (int tt = 0; tt < 4; ++tt)
        xs[tt] = __builtin_fmaf(sg[tt], dv[2][tt], xs[tt]) + p3[tt];
      __builtin_nontemporal_store(xs, (fvec4*)(ob + 2 * BD));
#pragma unroll
      for (int tt = 0; tt < 4; ++tt)
        xs[tt] = __builtin_fmaf(sg[tt], dv[3][tt], xs[tt]) + p4[tt];
      __builtin_nontemporal_store(xs, (fvec4*)(ob + 3 * BD));
      // x row for next tile
      *(usvec4*)&xb[wb][XIDX(xrow, c0)] =
          (usvec4){f2bf(xs[0]), f2bf(xs[1]), f2bf(xs[2]), f2bf(xs[3])};
      dv[0] = pf[0]; dv[1] = pf[1]; dv[2] = pf[2]; dv[3] = pf[3];
    } else {
      nus[0] = pf[0]; nus[1] = pf[1]; nus[2] = pf[2];
    }

    lds_barrier();
  }
}

extern "C" void kernel_launch(void* const* d_in, const int* in_sizes, int n_in,
                              void* d_out, int out_size, void* d_ws, size_t ws_size,
                              hipStream_t stream) {
  const float* x0    = (const float*)d_in[0];
  const float* Amat  = (const float*)d_in[1];
  const float* sigma = (const float*)d_in[2];
  const float* dW    = (const float*)d_in[3];
  float* out = (float*)d_out;
  sde_em_kernel<<<dim3(512), dim3(256), 0, stream>>>(x0, Amat, sigma, dW, out);
}

// Round 17
// 419.821 us; speedup vs baseline: 1.5669x; 1.5669x over previous
//
#include <hip/hip_runtime.h>
#include <hip/hip_bf16.h>

// SDE Euler-Maruyama: x_{k+1} = x_k + dt*(x_k @ A^T) + (sigma*sqrt(dt))*dW_k
// out[0] = x0, out[k+1] = x_{k+1}, out shape [1001, 1024, 256].
//
// R11 440 / R12 408 / R14 424 / R15 419 (4-step, 1 blk/CU plateau) /
// R16 657 (split-role 2blk/CU: DUPLICATED dW fetch +75%, 2x MFMA — both bugs).
// R17: 8-STEP FUSION, 2 paths/block, 512 blocks = 2 blk/CU ANTI-PHASE.
// Rows R = 8p + j, j in {x, nu0..nu6}: 16 rows, fully packed -> MFMA/CU/step
// == R12. Group q = (path q>>1, half q&1): low half holds t0..t3 (y1..y4
// from x), high half holds t4..t7; both compute local prefixes in parallel,
// one shfl_xor(16) of (P4, y4) finishes y5..y8; y8 shuffles back as next x.
// Each half loads its own 4 dW steps ONCE and stages its own 4 tile rows.
// Independent per-block barriers cover the ~700cyc/iter serial chain.
//   y_k = y_{k-1} + p_k + nu_{k-1}, p_k = t0+..+t_{k-1}, t = (dt*A)*row
//   (O(M^2) dropped, ~1e-4 accumulated vs 0.031 bf16 error)

typedef __attribute__((ext_vector_type(2))) float fvec2;
typedef __attribute__((ext_vector_type(4))) float fvec4;
typedef __attribute__((ext_vector_type(4))) unsigned short usvec4;
typedef __attribute__((ext_vector_type(8))) short svec8;
typedef __attribute__((ext_vector_type(4))) float f32x4;

constexpr int D = 256;
constexpr int BATCH = 1024;
constexpr int BD = BATCH * D;
constexpr int NSTEPS = 1000;
constexpr float DT = 0.001f;
constexpr float SQRT_DT = 0.03162277660168379f;  // sqrt(0.001)

__device__ __forceinline__ unsigned short f2bf(float f) {
  unsigned int u = __float_as_uint(f);
  u += 0x7FFFu + ((u >> 16) & 1u);
  return (unsigned short)(u >> 16);
}

// LDS-only barrier: no vmcnt drain (global loads/stores stay in flight).
__device__ __forceinline__ void lds_barrier() {
  __builtin_amdgcn_sched_barrier(0);
  asm volatile("s_waitcnt lgkmcnt(0)" ::: "memory");
  __builtin_amdgcn_s_barrier();
  __builtin_amdgcn_sched_barrier(0);
}

// xb u16 index for (row R, col c), XOR-swizzled (proven form from R12-R15;
// XOR hits col bits >=5 so 4-col and 8-col aligned runs stay contiguous)
#define XIDX(R, c) (((R) << 8) + ((c) ^ (((R)&7) << 5)))

__global__ __launch_bounds__(256, 2)
void sde_em_kernel(const float* __restrict__ x0, const float* __restrict__ Amat,
                   const float* __restrict__ sigma, const float* __restrict__ dW,
                   float* __restrict__ out) {
  // 16 rows (R = 8*path + j) x 256 cols bf16, double-buffered (16 KB)
  __shared__ __align__(16) unsigned short xb[2][16 * 256];

  const int t = threadIdx.x;
  const int w = t >> 6;          // wave 0..3: owns out-cols w*64 .. w*64+63
  const int l = t & 63;
  const int l16 = l & 15;
  const int q = l >> 4;          // lane group 0..3
  const int p = q >> 1;          // path within block (0/1)
  const int h = q & 1;           // 0: steps 1-4 (t0..t3), 1: steps 5-8 (t4..t7)

  // ---- one-time: B = DT*A^T fragments; chain tt -> out col c0 + tt ----
  svec8 bfr[4][8];
#pragma unroll
  for (int tt = 0; tt < 4; ++tt) {
#pragma unroll
    for (int kt = 0; kt < 8; ++kt) {
      const float* src =
          Amat + (size_t)((w << 6) + (l16 << 2) + tt) * D + (kt << 5) + (q << 3);
      fvec4 a0 = *(const fvec4*)(src);
      fvec4 a1 = *(const fvec4*)(src + 4);
      svec8 b;
      b[0] = (short)f2bf(DT * a0[0]); b[1] = (short)f2bf(DT * a0[1]);
      b[2] = (short)f2bf(DT * a0[2]); b[3] = (short)f2bf(DT * a0[3]);
      b[4] = (short)f2bf(DT * a1[0]); b[5] = (short)f2bf(DT * a1[1]);
      b[6] = (short)f2bf(DT * a1[2]); b[7] = (short)f2bf(DT * a1[3]);
      bfr[tt][kt] = b;
    }
  }

  // ---- per-lane: path p, 4 adjacent cols c0..c0+3, half h ----
  const int c0 = (w << 6) + (l16 << 2);
  const size_t go = (size_t)((blockIdx.x << 1) + p) * D + c0;
  fvec4 sg = *(const fvec4*)(sigma + c0);
  sg *= SQRT_DT;
  fvec4 xs = *(const fvec4*)(x0 + go);   // only low half's is live state

  // this half's 4 noise steps: dv[j] = dW[n + 4h + j]
  fvec4 dv[4];
#pragma unroll
  for (int j = 0; j < 4; ++j)
    dv[j] = __builtin_nontemporal_load(
        (const fvec4*)(dW + (size_t)((h << 2) + j) * BD + go));

  // seed xb[0]: rows pr+0 (x), pr+1..7 (nu for steps 0..6)
  const int pr = p << 3;
  if (!h) {
    *(usvec4*)&xb[0][XIDX(pr, c0)] =
        (usvec4){f2bf(xs[0]), f2bf(xs[1]), f2bf(xs[2]), f2bf(xs[3])};
#pragma unroll
    for (int j = 0; j < 4; ++j)
      *(usvec4*)&xb[0][XIDX(pr + 1 + j, c0)] =
          (usvec4){f2bf(sg[0] * dv[j][0]), f2bf(sg[1] * dv[j][1]),
                   f2bf(sg[2] * dv[j][2]), f2bf(sg[3] * dv[j][3])};
  } else {
#pragma unroll
    for (int j = 0; j < 3; ++j)
      *(usvec4*)&xb[0][XIDX(pr + 5 + j, c0)] =
          (usvec4){f2bf(sg[0] * dv[j][0]), f2bf(sg[1] * dv[j][1]),
                   f2bf(sg[2] * dv[j][2]), f2bf(sg[3] * dv[j][3])};
  }

  // out[0] = x0 (block slice = 2 paths x 256 dims; fvec2/thread, coalesced)
  {
    const size_t g2 = (size_t)(blockIdx.x << 1) * D + (t << 1);
    fvec2 v = *(const fvec2*)(x0 + g2);
    __builtin_nontemporal_store(v, (fvec2*)(out + g2));
  }

  __syncthreads();

  for (int it = 0; it < NSTEPS / 8; ++it) {
    const int n = it << 3;
    const int rb = it & 1, wb = rb ^ 1;

    // prefetch this half's next-iter noises: steps n+8+4h .. +3 (loaded ONCE)
    fvec4 pf[4];
#pragma unroll
    for (int j = 0; j < 4; ++j) {
      int st = n + 8 + (h << 2) + j;
      st = (st < NSTEPS) ? st : (NSTEPS - 1);
      pf[j] = __builtin_nontemporal_load(
          (const fvec4*)(dW + (size_t)st * BD + go));
    }

    // MFMA: group q's regs = t_{4h}..t_{4h+3} for path p, cols c0..c0+3
    f32x4 acc[4];
    acc[0] = (f32x4){0.f, 0.f, 0.f, 0.f};
    acc[1] = (f32x4){0.f, 0.f, 0.f, 0.f};
    acc[2] = (f32x4){0.f, 0.f, 0.f, 0.f};
    acc[3] = (f32x4){0.f, 0.f, 0.f, 0.f};
#pragma unroll
    for (int kt = 0; kt < 8; ++kt) {
      svec8 a = *(const svec8*)
          &xb[rb][XIDX(l16, (kt << 5) + (q << 3))];
#pragma unroll
      for (int tt = 0; tt < 4; ++tt)
        acc[tt] = __builtin_amdgcn_mfma_f32_16x16x32_bf16(a, bfr[tt][kt],
                                                          acc[tt], 0, 0, 0);
    }

    // local prefix (both halves in parallel): pk = sum t, zk[k] = partial y
    fvec4 pk = (fvec4){0.f, 0.f, 0.f, 0.f};
    fvec4 z = (fvec4){0.f, 0.f, 0.f, 0.f};
    fvec4 zk[4];
#pragma unroll
    for (int k = 0; k < 4; ++k) {
#pragma unroll
      for (int tt = 0; tt < 4; ++tt) {
        pk[tt] += acc[tt][k];
        z[tt] += pk[tt] + sg[tt] * dv[k][tt];
      }
      zk[k] = z;
    }

    // low half: y_k = x + zk  (steps n+1..n+4)
    if (!h) {
      float* ob = out + (size_t)(n + 1) * BD + go;
#pragma unroll
      for (int k = 0; k < 4; ++k)
        __builtin_nontemporal_store(xs + zk[k], (fvec4*)(ob + k * BD));
    }

    // exchange (P4, y4): low -> high (uniform code, masked use)
    fvec4 sendY = xs + zk[3];
    fvec4 recvP, recvY;
#pragma unroll
    for (int tt = 0; tt < 4; ++tt) {
      recvP[tt] = __shfl_xor(pk[tt], 16);
      recvY[tt] = __shfl_xor(sendY[tt], 16);
    }

    // high half: y_{4+k} = y4 + (k+1)*P4 + zk[k]  (steps n+5..n+8)
    fvec4 base = recvY, v;
    {
      float* ob = out + (size_t)(n + 5) * BD + go;
#pragma unroll
      for (int k = 0; k < 4; ++k) {
        base += recvP;
        v = base + zk[k];
        if (h) __builtin_nontemporal_store(v, (fvec4*)(ob + k * BD));
      }
    }
    // v = y8 in high lanes; hand back to low as next x
    fvec4 nx;
#pragma unroll
    for (int tt = 0; tt < 4; ++tt) nx[tt] = __shfl_xor(v[tt], 16);
    xs = h ? v : nx;   // both halves now hold y8 (high keeps its own)

    // stage next tile (each half writes 4 rows; every value staged once)
    if (!h) {
#pragma unroll
      for (int j = 0; j < 4; ++j)
        *(usvec4*)&xb[wb][XIDX(pr + 1 + j, c0)] =
            (usvec4){f2bf(sg[0] * pf[j][0]), f2bf(sg[1] * pf[j][1]),
                     f2bf(sg[2] * pf[j][2]), f2bf(sg[3] * pf[j][3])};
    } else {
#pragma unroll
      for (int j = 0; j < 3; ++j)
        *(usvec4*)&xb[wb][XIDX(pr + 5 + j, c0)] =
            (usvec4){f2bf(sg[0] * pf[j][0]), f2bf(sg[1] * pf[j][1]),
                     f2bf(sg[2] * pf[j][2]), f2bf(sg[3] * pf[j][3])};
      *(usvec4*)&xb[wb][XIDX(pr, c0)] =
          (usvec4){f2bf(xs[0]), f2bf(xs[1]), f2bf(xs[2]), f2bf(xs[3])};
    }

    dv[0] = pf[0]; dv[1] = pf[1]; dv[2] = pf[2]; dv[3] = pf[3];
    lds_barrier();
  }
}

extern "C" void kernel_launch(void* const* d_in, const int* in_sizes, int n_in,
                              void* d_out, int out_size, void* d_ws, size_t ws_size,
                              hipStream_t stream) {
  const float* x0    = (const float*)d_in[0];
  const float* Amat  = (const float*)d_in[1];
  const float* sigma = (const float*)d_in[2];
  const float* dW    = (const float*)d_in[3];
  float* out = (float*)d_out;
  sde_em_kernel<<<dim3(512), dim3(256), 0, stream>>>(x0, Amat, sigma, dW, out);
}

// Round 19
// 408.812 us; speedup vs baseline: 1.6091x; 1.0269x over previous
//
#include <hip/hip_runtime.h>
#include <hip/hip_bf16.h>

// SDE Euler-Maruyama: x_{k+1} = x_k + dt*(x_k @ A^T) + (sigma*sqrt(dt))*dW_k
// out[0] = x0, out[k+1] = x_{k+1}, out shape [1001, 1024, 256].
//
// R12 structure (best, 408us) + HARDENED BARRIER (R18 post-mortem): the old
// lds_barrier had asm(waitcnt) and a SEPARATE s_barrier builtin; LLVM's
// s.barrier is not a memory fence, so LDS ops could migrate between the
// waitcnt and the barrier -> rare cross-wave race (R18 failed post-timing
// revalidation at absmax 3.62 after passing first launch). Fix: waitcnt and
// s_barrier fused in ONE asm volatile block with "memory" clobber — no
// memory op can cross or split the pair.
//
// Structure: FUSED 4-STEP, fully-packed 16-row MFMA tile. M = dt*A:
//   y1 = x + Mx + nu0;  y2 = y1 + (Mx+Mnu0) + nu1;
//   y3 = y2 + (Mx+Mnu0+Mnu1) + nu2;  y4 = y3 + (Mx+..+Mnu2) + nu3
//   [O(M^2) dropped: ~1e-4 accumulated, vs 0.031 bf16 error]
// A rows R=4g+p: quantity g in {x, nu_n, nu_n+1, nu_n+2}, path p. C/D group
// g = quantity g, reg = path. 2-stage butterfly (shfl_xor 16, 32) transposes
// so lane group q gets all 4 quantities for path q. One MFMA pass / 4 steps.
// 256 blocks x 512 thr (2 waves/SIMD); register-resident bf16 B-frags;
// double-buffered XOR-swizzled LDS x/nu tile; lgkm-only fused barrier
// (1/iter); 7-deep rolling dW window; nontemporal streaming I/O.

typedef __attribute__((ext_vector_type(2))) float fvec2;
typedef __attribute__((ext_vector_type(4))) float fvec4;
typedef __attribute__((ext_vector_type(8))) short svec8;
typedef __attribute__((ext_vector_type(4))) float f32x4;

constexpr int D = 256;
constexpr int BATCH = 1024;
constexpr int BD = BATCH * D;
constexpr int NSTEPS = 1000;
constexpr float DT = 0.001f;
constexpr float SQRT_DT = 0.03162277660168379f;  // sqrt(0.001)

__device__ __forceinline__ unsigned short f2bf(float f) {
  unsigned int u = __float_as_uint(f);
  u += 0x7FFFu + ((u >> 16) & 1u);
  return (unsigned short)(u >> 16);
}

// LDS-only barrier: waits this wave's LDS ops, then syncs the workgroup.
// waitcnt+s_barrier are ONE opaque asm unit with memory clobber: no LDS op
// can be scheduled between them or cross them (IR or MI level). Global
// loads/stores stay in flight (no vmcnt drain).
__device__ __forceinline__ void lds_barrier() {
  __builtin_amdgcn_sched_barrier(0);
  asm volatile("s_waitcnt lgkmcnt(0)\n\ts_barrier" ::: "memory");
  __builtin_amdgcn_sched_barrier(0);
}

// xb u16 index for (row R, col c), XOR-swizzled
#define XIDX(R, c) ((((R) << 8)) + ((c) ^ (((R)&7) << 5)))

__global__ __launch_bounds__(512, 2)
void sde_em_kernel(const float* __restrict__ x0, const float* __restrict__ Amat,
                   const float* __restrict__ sigma, const float* __restrict__ dW,
                   float* __restrict__ out) {
  // xb: 16 rows (R = 4g+p) x 256 cols bf16, double-buffered (16 KB)
  __shared__ __align__(16) unsigned short xb[2][16 * 256];

  const int t = threadIdx.x;
  const int w = t >> 6;          // wave 0..7: owns cols w*32 .. w*32+31
  const int l = t & 63;
  const int l16 = l & 15;
  const int q = l >> 4;          // lane group 0..3 (frag k-slot; update path)
  const int bq = q & 1;          // bit0(q)
  const int Bq = q >> 1;         // bit1(q)

  // ---- one-time: B = DT*A^T fragments, bf16, registers ----
  svec8 bfr[2][8];
#pragma unroll
  for (int tt = 0; tt < 2; ++tt) {
#pragma unroll
    for (int kt = 0; kt < 8; ++kt) {
      const float* src =
          Amat + (size_t)((w << 5) + (tt << 4) + l16) * D + (kt << 5) + (q << 3);
      fvec4 a0 = *(const fvec4*)(src);
      fvec4 a1 = *(const fvec4*)(src + 4);
      svec8 b;
      b[0] = (short)f2bf(DT * a0[0]); b[1] = (short)f2bf(DT * a0[1]);
      b[2] = (short)f2bf(DT * a0[2]); b[3] = (short)f2bf(DT * a0[3]);
      b[4] = (short)f2bf(DT * a1[0]); b[5] = (short)f2bf(DT * a1[1]);
      b[6] = (short)f2bf(DT * a1[2]); b[7] = (short)f2bf(DT * a1[3]);
      bfr[tt][kt] = b;
    }
  }

  // ---- update role: lane (group q, l16) owns path q, cols c0, c0+16 ----
  const int c0 = (w << 5) + l16;
  const size_t go = (size_t)((blockIdx.x << 2) + q) * D + c0;
  const float sg0 = sigma[c0] * SQRT_DT;
  const float sg1 = sigma[c0 + 16] * SQRT_DT;
  float xs0 = x0[go];
  float xs1 = x0[go + 16];

  // rolling dW window: dwv[i] = dW[step n+i], i = 0..6
  float dv0[7], dv1[7];
#pragma unroll
  for (int i = 0; i < 7; ++i) {
    dv0[i] = __builtin_nontemporal_load(dW + (size_t)i * BD + go);
    dv1[i] = __builtin_nontemporal_load(dW + (size_t)i * BD + go + 16);
  }

  // seed xb[0]: x rows (R=q), nu rows (R=4+q, 8+q, 12+q from steps 0,1,2)
  xb[0][XIDX(q, c0)] = f2bf(xs0);
  xb[0][XIDX(q, c0 + 16)] = f2bf(xs1);
  xb[0][XIDX(4 + q, c0)] = f2bf(sg0 * dv0[0]);
  xb[0][XIDX(4 + q, c0 + 16)] = f2bf(sg1 * dv1[0]);
  xb[0][XIDX(8 + q, c0)] = f2bf(sg0 * dv0[1]);
  xb[0][XIDX(8 + q, c0 + 16)] = f2bf(sg1 * dv1[1]);
  xb[0][XIDX(12 + q, c0)] = f2bf(sg0 * dv0[2]);
  xb[0][XIDX(12 + q, c0 + 16)] = f2bf(sg1 * dv1[2]);

  // out[0] = x0 (vectorized copy, all 512 threads)
  {
    const int p2 = t >> 7;
    const int c2 = (t & 127) << 1;
    const size_t g2 = (size_t)((blockIdx.x << 2) + p2) * D + c2;
    fvec2 v = *(const fvec2*)(x0 + g2);
    __builtin_nontemporal_store(v, (fvec2*)(out + g2));
  }

  __syncthreads();

  // selq: pick by lane group q (uniform per 16 lanes -> cndmask chain)
#define SELQ(r, a0_, a1_, a2_, a3_)                                            \
  float r = a0_;                                                               \
  r = (q == 1) ? a1_ : r;                                                      \
  r = (q == 2) ? a2_ : r;                                                      \
  r = (q == 3) ? a3_ : r;

  // butterfly transpose: acc[p] = Q_q[path p] -> T_g = Q_g[path q]
#define XPOSE(A, T0, T1, T2, T3)                                               \
  const float u1_##T0 = __shfl_xor(bq ? A[0] : A[1], 16);                      \
  const float u2_##T0 = __shfl_xor(bq ? A[2] : A[3], 16);                      \
  const float k1_##T0 = bq ? A[1] : A[0];                                      \
  const float k2_##T0 = bq ? A[3] : A[2];                                      \
  const float v1_##T0 = __shfl_xor(Bq ? k1_##T0 : k2_##T0, 32);                \
  const float v2_##T0 = __shfl_xor(Bq ? u1_##T0 : u2_##T0, 32);                \
  const float tq_##T0 = Bq ? k2_##T0 : k1_##T0;                                \
  const float tu_##T0 = Bq ? u2_##T0 : u1_##T0;                                \
  SELQ(T0, tq_##T0, tu_##T0, v1_##T0, v2_##T0)                                 \
  SELQ(T1, tu_##T0, tq_##T0, v2_##T0, v1_##T0)                                 \
  SELQ(T2, v1_##T0, v2_##T0, tq_##T0, tu_##T0)                                 \
  SELQ(T3, v2_##T0, v1_##T0, tu_##T0, tq_##T0)

#define ITER(n_, RB, WB)                                                       \
  {                                                                            \
    /* prefetch dW[n+7 .. n+10] (fills window tail after roll) */              \
    float pf0[4], pf1[4];                                                      \
    _Pragma("unroll") for (int j = 0; j < 4; ++j) {                            \
      int i_ = (n_) + 7 + j;                                                   \
      i_ = (i_ < NSTEPS) ? i_ : (NSTEPS - 1);                                  \
      pf0[j] = __builtin_nontemporal_load(dW + (size_t)i_ * BD + go);          \
      pf1[j] = __builtin_nontemporal_load(dW + (size_t)i_ * BD + go + 16);     \
    }                                                                          \
    f32x4 acc0 = (f32x4){0.f, 0.f, 0.f, 0.f};                                  \
    f32x4 acc1 = (f32x4){0.f, 0.f, 0.f, 0.f};                                  \
    _Pragma("unroll") for (int kt = 0; kt < 8; ++kt) {                         \
      svec8 a = *(const svec8*)                                                \
          &xb[RB][(l16 << 8) + (((kt << 5) + (q << 3)) ^ ((l16 & 7) << 5))];   \
      acc0 = __builtin_amdgcn_mfma_f32_16x16x32_bf16(a, bfr[0][kt], acc0,      \
                                                     0, 0, 0);                 \
      acc1 = __builtin_amdgcn_mfma_f32_16x16x32_bf16(a, bfr[1][kt], acc1,      \
                                                     0, 0, 0);                 \
    }                                                                          \
    XPOSE(acc0, tA0, tA1, tA2, tA3)                                            \
    XPOSE(acc1, tB0, tB1, tB2, tB3)                                            \
    const float p1A = tA0, p2A = p1A + tA1, p3A = p2A + tA2, p4A = p3A + tA3;  \
    const float p1B = tB0, p2B = p1B + tB1, p3B = p2B + tB2, p4B = p3B + tB3;  \
    float* ob_ = out + (size_t)((n_) + 1) * BD + go;                           \
    xs0 = __builtin_fmaf(sg0, dv0[0], xs0) + p1A;                              \
    xs1 = __builtin_fmaf(sg1, dv1[0], xs1) + p1B;                              \
    __builtin_nontemporal_store(xs0, ob_);                                     \
    __builtin_nontemporal_store(xs1, ob_ + 16);                                \
    xs0 = __builtin_fmaf(sg0, dv0[1], xs0) + p2A;                              \
    xs1 = __builtin_fmaf(sg1, dv1[1], xs1) + p2B;                              \
    __builtin_nontemporal_store(xs0, ob_ + BD);                                \
    __builtin_nontemporal_store(xs1, ob_ + BD + 16);                           \
    xs0 = __builtin_fmaf(sg0, dv0[2], xs0) + p3A;                              \
    xs1 = __builtin_fmaf(sg1, dv1[2], xs1) + p3B;                              \
    __builtin_nontemporal_store(xs0, ob_ + 2 * BD);                            \
    __builtin_nontemporal_store(xs1, ob_ + 2 * BD + 16);                       \
    xs0 = __builtin_fmaf(sg0, dv0[3], xs0) + p4A;                              \
    xs1 = __builtin_fmaf(sg1, dv1[3], xs1) + p4B;                              \
    __builtin_nontemporal_store(xs0, ob_ + 3 * BD);                            \
    __builtin_nontemporal_store(xs1, ob_ + 3 * BD + 16);                       \
    /* next tile: x = y4; nu from steps n+4, n+5, n+6 (dv[4..6]) */            \
    xb[WB][XIDX(q, c0)] = f2bf(xs0);                                           \
    xb[WB][XIDX(q, c0 + 16)] = f2bf(xs1);                                      \
    xb[WB][XIDX(4 + q, c0)] = f2bf(sg0 * dv0[4]);                              \
    xb[WB][XIDX(4 + q, c0 + 16)] = f2bf(sg1 * dv1[4]);                         \
    xb[WB][XIDX(8 + q, c0)] = f2bf(sg0 * dv0[5]);                              \
    xb[WB][XIDX(8 + q, c0 + 16)] = f2bf(sg1 * dv1[5]);                         \
    xb[WB][XIDX(12 + q, c0)] = f2bf(sg0 * dv0[6]);                             \
    xb[WB][XIDX(12 + q, c0 + 16)] = f2bf(sg1 * dv1[6]);                        \
    /* roll window by 4 */                                                     \
    dv0[0] = dv0[4]; dv0[1] = dv0[5]; dv0[2] = dv0[6];                         \
    dv0[3] = pf0[0]; dv0[4] = pf0[1]; dv0[5] = pf0[2]; dv0[6] = pf0[3];        \
    dv1[0] = dv1[4]; dv1[1] = dv1[5]; dv1[2] = dv1[6];                         \
    dv1[3] = pf1[0]; dv1[4] = pf1[1]; dv1[5] = pf1[2]; dv1[6] = pf1[3];        \
    lds_barrier();                                                             \
  }

  // 250 fused iterations (n = 0, 4, ..., 996), x2 unroll for buffer parity
  for (int k = 0; k < NSTEPS / 4; k += 2) {
    ITER(4 * k, 0, 1);
    ITER(4 * k + 4, 1, 0);
  }
#undef ITER
#undef XPOSE
#undef SELQ
}

extern "C" void kernel_launch(void* const* d_in, const int* in_sizes, int n_in,
                              void* d_out, int out_size, void* d_ws, size_t ws_size,
                              hipStream_t stream) {
  const float* x0    = (const float*)d_in[0];
  const float* Amat  = (const float*)d_in[1];
  const float* sigma = (const float*)d_in[2];
  const float* dW    = (const float*)d_in[3];
  float* out = (float*)d_out;
  sde_em_kernel<<<dim3(256), dim3(512), 0, stream>>>(x0, Amat, sigma, dW, out);
}